// Round 9
// baseline (500.830 us; speedup 1.0000x reference)
//
#include <hip/hip_runtime.h>
#include <hip/hip_bf16.h>

#define NBATCH 8
#define SQL 512
#define SKL 512
#define DD 32
#define KF 1152            // padded feature dim (real 1121)
#define UT 528             // D*(D+1)/2
#define NOUT 1056          // 32 mean cols + 1024 cov cols
#define NVT 1088           // Vt rows padded to 17*64
#define NSITE (NBATCH * SQL)        // 4096 per side
#define VS_BLOCKS (34 * 16 * NBATCH)

typedef short short8 __attribute__((ext_vector_type(8)));   // 8 bf16 bit-patterns
typedef float f32x4 __attribute__((ext_vector_type(4)));
typedef unsigned short ushort_t;

__device__ __forceinline__ ushort_t f2bf(float f) {          // fp32 -> bf16 bits, RNE
    unsigned int u = __float_as_uint(f);
    return (ushort_t)((u + 0x7fffu + ((u >> 16) & 1u)) >> 16);
}
__device__ __forceinline__ float bf2f(ushort_t h) {
    return __uint_as_float(((unsigned int)h) << 16);
}
__device__ __forceinline__ void gl_lds16(const ushort_t* g, ushort_t* l) {
    __builtin_amdgcn_global_load_lds(
        (const __attribute__((address_space(1))) void*)g,
        (__attribute__((address_space(3))) void*)l, 16, 0, 0);
}
// packed 2x fp32 -> bf16 hi bits + lo residual bits
__device__ __forceinline__ void pk_split(float v0, float v1, ushort_t& h0, ushort_t& h1,
                                         ushort_t& l0, ushort_t& l1) {
    __hip_bfloat162 H = __float22bfloat162_rn(make_float2(v0, v1));
    ushort2 hu = *(ushort2*)&H;
    h0 = hu.x; h1 = hu.y;
    __hip_bfloat162 L = __float22bfloat162_rn(make_float2(v0 - bf2f(hu.x), v1 - bf2f(hu.y)));
    ushort2 lu = *(ushort2*)&L;
    l0 = lu.x; l1 = lu.y;
}
// butterfly xor-M within each 32-lane half (and=0x1F)
template<int M>
__device__ __forceinline__ float swzx(float x) {
    return __int_as_float(__builtin_amdgcn_ds_swizzle(__float_as_int(x), (M << 10) | 0x1F));
}

// Symmetric SWEEP step (pivot P). Matrix stays symmetric every step, so the
// pivot column == pivot row == each lane's own a[P]: 1 ds_write_b32 + 8
// ds_read_b128 broadcasts per pivot. Register-frugal: each quad of the pivot
// row is consumed by 4 fmas immediately after its load (peak live set
// ~a[32]+quad, NOT a[32]+c[32] — R8's spill source).
// After all 32 sweeps, a[] = column hl of (-A^-1).  [math HW-verified in R8]
template<int P>
__device__ __forceinline__ void sweep_step(float (&a)[DD], int hl, float* pc) {
    pc[hl] = a[P];                         // share pivot row (in-order DS)
    const float4* pc4 = (const float4*)pc;
    constexpr int QP = P >> 2;
    float4 vq = pc4[QP];                   // quad holding the diagonal
    const float d = ((P & 3) == 0) ? vq.x : ((P & 3) == 1) ? vq.y
                  : ((P & 3) == 2) ? vq.z : vq.w;
    const float rinv = __builtin_amdgcn_rcpf(d);   // SPD, cond~2: rcp fine
    const float t = a[P] * rinv;
    const bool isp = (hl == P);
    const float alpha = isp ? 0.0f : 1.0f;
    const float beta  = isp ? rinv : -t;
    {   // consume the already-loaded pivot quad
        const float cv[4] = {vq.x, vq.y, vq.z, vq.w};
        #pragma unroll
        for (int k = 0; k < 4; ++k) {
            constexpr int base = QP * 4;
            if (base + k != P)
                a[base + k] = fmaf(cv[k], beta, a[base + k] * alpha);
        }
    }
    #pragma unroll
    for (int q = 0; q < 8; ++q) {
        if (q == QP) continue;
        float4 v = pc4[q];                 // load quad, consume immediately
        const int i0 = q * 4;
        a[i0 + 0] = fmaf(v.x, beta, a[i0 + 0] * alpha);
        a[i0 + 1] = fmaf(v.y, beta, a[i0 + 1] * alpha);
        a[i0 + 2] = fmaf(v.z, beta, a[i0 + 2] * alpha);
        a[i0 + 3] = fmaf(v.w, beta, a[i0 + 3] * alpha);
    }
    a[P] = isp ? -rinv : t;
}
template<int P>
__device__ __forceinline__ void sweep_run(float (&a)[DD], int hl, float* pc) {
    sweep_step<P>(a, hl, pc);
    if constexpr (P + 1 < DD) sweep_run<P + 1>(a, hl, pc);
}

// ---------------------------------------------------------------------------
// Kernel 1: per-site inversion + features. TWO matrices per wave (lanes 0-31
// = site s, 32-63 = site s+1), symmetric sweep with LDS pivot-row sharing.
// Inverse stored as packed upper triangle. All LDS wave-private -> no
// barriers. 8 matrices per 256-thread block, 1024 blocks.
// ---------------------------------------------------------------------------
__global__ __launch_bounds__(256, 4) void feat_kernel(
    const float* __restrict__ qm, const float* __restrict__ qc,
    const float* __restrict__ km, const float* __restrict__ kc,
    ushort_t* __restrict__ fqh, ushort_t* __restrict__ fql,
    ushort_t* __restrict__ fkh, ushort_t* __restrict__ fkl)
{
    __shared__ float smem[8 * 592];   // per matrix: 528 tri + 32 mu + 32 pc

    const int tid = threadIdx.x;
    const int wid = tid >> 6, lane = tid & 63;
    const int half = lane >> 5, hl = lane & 31;
    const int site_g = (blockIdx.x * 4 + wid) * 2 + half;   // 0..8191
    const int qside = site_g < NSITE;
    const int site = qside ? site_g : site_g - NSITE;

    const float* covp = (qside ? qc : kc) + (size_t)site * (DD * DD);
    const float* mup  = (qside ? qm : km) + (size_t)site * DD;
    ushort_t* fh = qside ? fqh : fkh;
    ushort_t* fl = qside ? fql : fkl;
    const size_t fo = (size_t)site * KF;

    float* base  = smem + (wid * 2 + half) * 592;
    float* inv_p = base;            // packed upper tri of Sigma^-1
    float* mu_s  = base + 528;
    float* pc    = base + 560;      // 16B-aligned (560*4 % 16 == 0)

    const float mu_lane = mup[hl];
    mu_s[hl] = mu_lane;

    float a[DD];
    #pragma unroll
    for (int r = 0; r < DD; ++r) a[r] = covp[r * DD + hl];

    sweep_run<0>(a, hl, pc);        // a[] = column hl of -Sigma^-1

    // packed upper-tri store of Sigma^-1 (negate W)
    #pragma unroll
    for (int r = 0; r < DD; ++r)
        if (r <= hl) inv_p[((r * (65 - r)) >> 1) + hl - r] = -a[r];

    // iv_c = (Sigma^-1 mu)_c from own column (symmetry)
    float s = 0.f;
    #pragma unroll
    for (int e = 0; e < DD; ++e) s = fmaf(a[e], mu_s[e], s);
    const float ivr = -s;

    // bias = mu^T Sigma^-1 mu : butterfly sum within half
    float pb = mu_lane * ivr;
    pb += swzx<1>(pb); pb += swzx<2>(pb); pb += swzx<4>(pb);
    pb += swzx<8>(pb); pb += swzx<16>(pb);
    const float bias = pb;

    // Packed upper-triangle features (q-side carries the 0.25 JSD scale).
    for (int idx = hl; idx < UT; idx += 32) {
        int d = (int)((65.0f - sqrtf(4225.0f - 8.0f * (float)idx)) * 0.5f);
        if (d > 0 && (d * (65 - d)) / 2 > idx) --d;
        if (((d + 1) * (64 - d)) / 2 <= idx) ++d;
        int off = (d * (65 - d)) / 2;
        int e = d + (idx - off);
        float Mv = covp[d * DD + e] + mu_s[d] * mu_s[e];
        float Iv = inv_p[idx];             // packed idx == feature idx
        float w = (d == e) ? 0.25f : 0.5f;
        float v0, v1;
        if (qside) { v0 = w * Mv; v1 = w * Iv; }
        else       { v0 = Iv;     v1 = Mv; }
        ushort_t h0, h1, l0, l1;
        pk_split(v0, v1, h0, h1, l0, l1);
        fh[fo + idx] = h0; fh[fo + UT + idx] = h1;
        fl[fo + idx] = l0; fl[fo + UT + idx] = l1;
    }
    {
        float v0, v1;
        if (qside) { v0 = -0.5f * ivr; v1 = 0.25f * mu_lane; }
        else       { v0 = mu_lane;     v1 = -2.f * ivr; }
        ushort_t h0, h1, l0, l1;
        pk_split(v0, v1, h0, h1, l0, l1);
        fh[fo + 2*UT + hl] = h0; fh[fo + 2*UT + DD + hl] = h1;
        fl[fo + 2*UT + hl] = l0; fl[fo + 2*UT + DD + hl] = l1;
    }
    if (hl == 0) {
        float v = qside ? 0.25f : bias;
        ushort_t hb = f2bf(v);
        fh[fo + 2*UT + 2*DD] = hb;
        fl[fo + 2*UT + 2*DD] = f2bf(v - bf2f(hb));
    }
    for (int i = 2*UT + 2*DD + 1 + hl; i < KF; i += 32) { fh[fo + i] = 0; fl[fo + i] = 0; }
}

// ---------------------------------------------------------------------------
// MFMA GEMM. MODE 0: score, A,B split hi/lo (3 MFMA/pair), split-K x2.
//   DUAL=1: kslice s plain-stores into Cs (no atomics, no pre-zero).
//   DUAL=0: atomicAdd into C0 (pre-zeroed) — ws-too-small fallback.
// MODE 1: output. A=P hi, B=Vt hi. Routed stores.
// ---------------------------------------------------------------------------
template<int MODE, int DUAL>
__global__ __launch_bounds__(256) void gemm_split(
    const ushort_t* __restrict__ Ah_g, const ushort_t* __restrict__ Al_g,
    const ushort_t* __restrict__ Bh_g, const ushort_t* __restrict__ Bl_g,
    float* __restrict__ C0, float* __restrict__ C1)
{
    constexpr bool SPLIT = (MODE == 0);
    constexpr int KSTRIDE = SPLIT ? KF : SKL;
    constexpr int KITERS = SPLIT ? (KF / 2 / 32) : (SKL / 32);
    const int b = blockIdx.z, nt = blockIdx.x;
    const int mt = SPLIT ? (blockIdx.y & 3) : blockIdx.y;
    const int ks = SPLIT ? (blockIdx.y >> 2) : 0;
    const int kbase = ks * (SPLIT ? (KF / 2) : 0);
    const int tid = threadIdx.x, lane = tid & 63, wid = tid >> 6;
    const int wm = wid & 1, wn = wid >> 1;
    const int BROWS = MODE ? NVT : SKL;

    const ushort_t* Ah = Ah_g + ((size_t)b * SQL + mt * 128) * KSTRIDE;
    const ushort_t* Al = Al_g + ((size_t)b * SQL + mt * 128) * KSTRIDE;
    const ushort_t* Bh = Bh_g + ((size_t)b * BROWS + nt * 64) * KSTRIDE;
    const ushort_t* Bl = Bl_g + ((size_t)b * BROWS + nt * 64) * KSTRIDE;

    __shared__ __align__(16) ushort_t AsH[128 * 32];
    __shared__ __align__(16) ushort_t AsL[SPLIT ? 128 * 32 : 8];
    __shared__ __align__(16) ushort_t BsH[64 * 32];
    __shared__ __align__(16) ushort_t BsL[SPLIT ? 64 * 32 : 8];

    const int r4 = lane >> 2, kp = (lane & 3) * 8;
    const int arow0 = wid * 16 + r4,        aoff0 = wid * 512 + lane * 8;
    const int arow1 = (wid + 4) * 16 + r4,  aoff1 = (wid + 4) * 512 + lane * 8;

    const int fm = lane & 15;
    const int q8 = (lane >> 4) * 8;

    f32x4 acc[4][2];
    #pragma unroll
    for (int i = 0; i < 4; ++i)
        #pragma unroll
        for (int j = 0; j < 2; ++j)
            acc[i][j] = (f32x4){0.f, 0.f, 0.f, 0.f};

    for (int it = 0; it < KITERS; ++it) {
        const int k0 = kbase + it * 32;
        __syncthreads();
        gl_lds16(Ah + (size_t)arow0 * KSTRIDE + k0 + kp, &AsH[aoff0]);
        gl_lds16(Ah + (size_t)arow1 * KSTRIDE + k0 + kp, &AsH[aoff1]);
        gl_lds16(Bh + (size_t)arow0 * KSTRIDE + k0 + kp, &BsH[aoff0]);
        if (SPLIT) {
            gl_lds16(Al + (size_t)arow0 * KSTRIDE + k0 + kp, &AsL[aoff0]);
            gl_lds16(Al + (size_t)arow1 * KSTRIDE + k0 + kp, &AsL[aoff1]);
            gl_lds16(Bl + (size_t)arow0 * KSTRIDE + k0 + kp, &BsL[aoff0]);
        }
        __syncthreads();

        short8 ah[4], al[4], bh[2], bl[2];
        #pragma unroll
        for (int i = 0; i < 4; ++i) {
            const int r = wm * 64 + i * 16 + fm;
            ah[i] = *(const short8*)&AsH[r * 32 + q8];
            if (SPLIT) al[i] = *(const short8*)&AsL[r * 32 + q8];
        }
        #pragma unroll
        for (int j = 0; j < 2; ++j) {
            const int r = wn * 32 + j * 16 + fm;
            bh[j] = *(const short8*)&BsH[r * 32 + q8];
            if (SPLIT) bl[j] = *(const short8*)&BsL[r * 32 + q8];
        }
        #pragma unroll
        for (int i = 0; i < 4; ++i)
            #pragma unroll
            for (int j = 0; j < 2; ++j) {
                acc[i][j] = __builtin_amdgcn_mfma_f32_16x16x32_bf16(ah[i], bh[j], acc[i][j], 0, 0, 0);
                if (SPLIT) {
                    acc[i][j] = __builtin_amdgcn_mfma_f32_16x16x32_bf16(ah[i], bl[j], acc[i][j], 0, 0, 0);
                    acc[i][j] = __builtin_amdgcn_mfma_f32_16x16x32_bf16(al[i], bh[j], acc[i][j], 0, 0, 0);
                }
            }
    }

    float* Cs = (SPLIT && DUAL && ks) ? C1 : C0;
    const int crow0 = (lane >> 4) * 4;
    const int ccol = lane & 15;
    #pragma unroll
    for (int i = 0; i < 4; ++i) {
        const int m = mt * 128 + wm * 64 + i * 16 + crow0;
        #pragma unroll
        for (int j = 0; j < 2; ++j) {
            const int n = nt * 64 + wn * 32 + j * 16 + ccol;
            #pragma unroll
            for (int r = 0; r < 4; ++r) {
                const float v = acc[i][j][r];
                const size_t rowb = (size_t)b * SQL + (m + r);
                if (MODE == 0) {
                    if (DUAL) Cs[rowb * SKL + n] = v;
                    else      atomicAdd(&C0[rowb * SKL + n], v);
                } else {
                    if (n < DD)        C0[rowb * DD + n] = v;
                    else if (n < NOUT) C1[rowb * (DD * DD) + (n - DD)] = v;
                }
            }
        }
    }
}

// ---------------------------------------------------------------------------
// Kernel 3 (merged): blocks [0,4096): row softmax (js0[+js1]) -> bf16 P.
// blocks [4096,..): Vt = [v_mean | v_cov]^T, bf16 hi, [n][k], zero-padded.
// ---------------------------------------------------------------------------
template<int DUAL>
__global__ __launch_bounds__(256) void phase2_kernel(
    const float* __restrict__ js0, const float* __restrict__ js1,
    ushort_t* __restrict__ ph,
    const float* __restrict__ vmean, const float* __restrict__ vcov,
    ushort_t* __restrict__ vth)
{
    __shared__ float sm[32 * 33];
    const int tid = threadIdx.x;
    if (blockIdx.x < (unsigned)(NBATCH * SQL)) {
        const size_t ro = (size_t)blockIdx.x * SKL + 2 * tid;
        float2 v = *(const float2*)(js0 + ro);
        if (DUAL) {
            float2 v1 = *(const float2*)(js1 + ro);
            v.x += v1.x; v.y += v1.y;
        }
        float m = fmaxf(v.x, v.y);
        #pragma unroll
        for (int o = 32; o > 0; o >>= 1) m = fmaxf(m, __shfl_xor(m, o));
        const int wid = tid >> 6, ln = tid & 63;
        if (ln == 0) sm[wid] = m;
        __syncthreads();
        m = fmaxf(fmaxf(sm[0], sm[1]), fmaxf(sm[2], sm[3]));
        float e0 = __expf(v.x - m), e1 = __expf(v.y - m);
        float s = e0 + e1;
        #pragma unroll
        for (int o = 32; o > 0; o >>= 1) s += __shfl_xor(s, o);
        if (ln == 0) sm[4 + wid] = s;
        __syncthreads();
        s = sm[4] + sm[5] + sm[6] + sm[7];
        float rs = 1.0f / s;
        ph[ro]     = f2bf(e0 * rs);
        ph[ro + 1] = f2bf(e1 * rs);
    } else {
        const int vb = blockIdx.x - NBATCH * SQL;
        const int b = vb / (34 * 16), rem = vb % (34 * 16);
        const int kt = rem / 34, nt = rem % 34;
        const int n0 = nt * 32, k0 = kt * 32;
        const int tx = tid & 31, ty = tid >> 5;
        for (int r = ty; r < 32; r += 8) {
            const int k = k0 + r, n = n0 + tx;
            float v;
            if (n0 == 0)          v = vmean[((size_t)b * SKL + k) * DD + n];
            else if (n0 >= NOUT)  v = 0.f;
            else                  v = vcov[((size_t)b * SKL + k) * (DD * DD) + (n - DD)];
            sm[tx * 33 + r] = v;
        }
        __syncthreads();
        for (int r = ty; r < 32; r += 8) {
            const int n = n0 + r, k = k0 + tx;
            vth[((size_t)b * NVT + n) * SKL + k] = f2bf(sm[r * 33 + tx]);
        }
    }
}

// ---------------------------------------------------------------------------
extern "C" void kernel_launch(void* const* d_in, const int* in_sizes, int n_in,
                              void* d_out, int out_size, void* d_ws, size_t ws_size,
                              hipStream_t stream)
{
    const float* q_mean = (const float*)d_in[0];
    const float* q_cov  = (const float*)d_in[1];
    const float* k_mean = (const float*)d_in[2];
    const float* k_cov  = (const float*)d_in[3];
    const float* v_mean = (const float*)d_in[4];
    const float* v_cov  = (const float*)d_in[5];

    float* out_mean = (float*)d_out;                        // [8,512,32]
    float* out_cov  = out_mean + (size_t)NBATCH * SQL * DD; // [8,512,32,32]

    // workspace: features (37.7MB) | js0 (8.4) | js1 (8.4)
    // After score gemm the feature arrays are dead: vt aliases fq, P aliases fk.
    char* w = (char*)d_ws;
    const size_t FQN = (size_t)NBATCH * SQL * KF;
    const size_t JSN = (size_t)NBATCH * SQL * SKL;
    ushort_t* fq_h = (ushort_t*)w;
    ushort_t* fq_l = fq_h + FQN;
    ushort_t* fk_h = fq_l + FQN;
    ushort_t* fk_l = fk_h + FQN;
    float*    js0  = (float*)(fk_l + FQN);
    float*    js1  = js0 + JSN;
    ushort_t* vt_h = fq_h;
    ushort_t* p_h  = fk_h;

    const bool dual = ws_size >= (8 * FQN + 8 * JSN);

    feat_kernel<<<2 * NSITE / 8, 256, 0, stream>>>(
        q_mean, q_cov, k_mean, k_cov, fq_h, fq_l, fk_h, fk_l);
    if (dual) {
        gemm_split<0, 1><<<dim3(SKL / 64, 8, NBATCH), 256, 0, stream>>>(
            fq_h, fq_l, fk_h, fk_l, js0, js1);
        phase2_kernel<1><<<NBATCH * SQL + VS_BLOCKS, 256, 0, stream>>>(
            js0, js1, p_h, v_mean, v_cov, vt_h);
    } else {
        hipMemsetAsync(js0, 0, JSN * sizeof(float), stream);
        gemm_split<0, 0><<<dim3(SKL / 64, 8, NBATCH), 256, 0, stream>>>(
            fq_h, fq_l, fk_h, fk_l, js0, nullptr);
        phase2_kernel<0><<<NBATCH * SQL + VS_BLOCKS, 256, 0, stream>>>(
            js0, nullptr, p_h, v_mean, v_cov, vt_h);
    }
    gemm_split<1, 0><<<dim3(NVT / 64, SQL / 128, NBATCH), 256, 0, stream>>>(
        p_h, nullptr, vt_h, nullptr, out_mean, out_cov);
}

// Round 10
// 184.282 us; speedup vs baseline: 2.7177x; 2.7177x over previous
//
#include <hip/hip_runtime.h>
#include <hip/hip_bf16.h>

#define NBATCH 8
#define SQL 512
#define SKL 512
#define DD 32
#define KF 1152            // padded feature dim (real 1121)
#define UT 528             // D*(D+1)/2
#define NOUT 1056          // 32 mean cols + 1024 cov cols
#define NVT 1088           // Vt rows padded to 17*64
#define NSITE (NBATCH * SQL)        // 4096 per side
#define FEAT_BLOCKS (2 * NSITE / 8) // 1024 blocks, 8 matrices each
#define VS_BLOCKS (34 * 16 * NBATCH)

typedef short short8 __attribute__((ext_vector_type(8)));   // 8 bf16 bit-patterns
typedef float f32x4 __attribute__((ext_vector_type(4)));
typedef unsigned short ushort_t;

__device__ __forceinline__ ushort_t f2bf(float f) {          // fp32 -> bf16 bits, RNE
    unsigned int u = __float_as_uint(f);
    return (ushort_t)((u + 0x7fffu + ((u >> 16) & 1u)) >> 16);
}
__device__ __forceinline__ float bf2f(ushort_t h) {
    return __uint_as_float(((unsigned int)h) << 16);
}
__device__ __forceinline__ void gl_lds16(const ushort_t* g, ushort_t* l) {
    __builtin_amdgcn_global_load_lds(
        (const __attribute__((address_space(1))) void*)g,
        (__attribute__((address_space(3))) void*)l, 16, 0, 0);
}
// packed 2x fp32 -> bf16 hi bits + lo residual bits
__device__ __forceinline__ void pk_split(float v0, float v1, ushort_t& h0, ushort_t& h1,
                                         ushort_t& l0, ushort_t& l1) {
    __hip_bfloat162 H = __float22bfloat162_rn(make_float2(v0, v1));
    ushort2 hu = *(ushort2*)&H;
    h0 = hu.x; h1 = hu.y;
    __hip_bfloat162 L = __float22bfloat162_rn(make_float2(v0 - bf2f(hu.x), v1 - bf2f(hu.y)));
    ushort2 lu = *(ushort2*)&L;
    l0 = lu.x; l1 = lu.y;
}

// ds_swizzle BitMode broadcast of lane P within each 32-lane half
template<int P>
__device__ __forceinline__ float swzb(float x) {
    return __int_as_float(__builtin_amdgcn_ds_swizzle(__float_as_int(x), (P << 5)));
}
// butterfly xor-M within each 32-lane half (and=0x1F)
template<int M>
__device__ __forceinline__ float swzx(float x) {
    return __int_as_float(__builtin_amdgcn_ds_swizzle(__float_as_int(x), (M << 10) | 0x1F));
}

// In-place symmetric GJ sweep, one pivot (R6-proven: VGPR=52, no spill).
// Lane hl (0..31 per half) holds column hl. After 32 pivots, a[] = column hl
// of A^-1. Broadcasts via ds_swizzle: register-to-register on the DS pipe,
// no LDS aliasing -> compiler keeps a[32] in VGPRs (unlike LDS round-trip
// variants, which spill — R8/R9 post-mortem).
template<int P>
__device__ __forceinline__ void gj_step(float (&a)[DD], int hl) {
    float piv = swzb<P>(a[P]);
    float rinv = __builtin_amdgcn_rcpf(piv);   // SPD, cond~2: rcp fine
    float t = a[P] * rinv;
    bool isp = (hl == P);
    float u = isp ? rinv : t;
    float g = isp ? 0.0f : 1.0f;
    #pragma unroll
    for (int i = 0; i < DD; ++i) {
        if (i == P) continue;
        float ci = swzb<P>(a[i]);              // a_iP (per half), pre-update
        a[i] = fmaf(a[i], g, -(ci * u));
    }
    a[P] = u;
}
template<int P>
__device__ __forceinline__ void gj_run(float (&a)[DD], int hl) {
    gj_step<P>(a, hl);
    if constexpr (P + 1 < DD) gj_run<P + 1>(a, hl);
}

// ---------------------------------------------------------------------------
// Kernel 1 (fused): blocks [0,1024): per-site inversion + bf16 hi/lo features
// (8 matrices/block, 2 per wave, swizzle GJ, wave-private LDS, no barriers).
// blocks [1024,..): Vt = [v_mean|v_cov]^T transpose to bf16 — independent
// memory-bound work backfilling CU slots while feat's serial chains stall.
// ---------------------------------------------------------------------------
__global__ __launch_bounds__(256, 4) void feat_fused(
    const float* __restrict__ qm, const float* __restrict__ qc,
    const float* __restrict__ km, const float* __restrict__ kc,
    ushort_t* __restrict__ fqh, ushort_t* __restrict__ fql,
    ushort_t* __restrict__ fkh, ushort_t* __restrict__ fkl,
    const float* __restrict__ vmean, const float* __restrict__ vcov,
    ushort_t* __restrict__ vth)
{
    __shared__ float smem[8 * 1064 + 8 * 32];   // feat: 8x(32x33 inv) + 8x32 mu
    const int tid = threadIdx.x;

    if (blockIdx.x < FEAT_BLOCKS) {
        const int wid = tid >> 6, lane = tid & 63;
        const int half = lane >> 5, hl = lane & 31;
        const int site_g = (blockIdx.x * 4 + wid) * 2 + half;   // 0..8191
        const int qside = site_g < NSITE;
        const int site = qside ? site_g : site_g - NSITE;

        const float* covp = (qside ? qc : kc) + (size_t)site * (DD * DD);
        const float* mup  = (qside ? qm : km) + (size_t)site * DD;
        ushort_t* fh = qside ? fqh : fkh;
        ushort_t* fl = qside ? fql : fkl;
        const size_t fo = (size_t)site * KF;

        float* inv_s = smem + (wid * 2 + half) * 1064;          // row stride 33
        float* mu_s  = smem + 8 * 1064 + (wid * 2 + half) * 32;

        const float mu_lane = mup[hl];
        mu_s[hl] = mu_lane;

        float a[DD];
        #pragma unroll
        for (int r = 0; r < DD; ++r) a[r] = covp[r * DD + hl];

        gj_run<0>(a, hl);              // a[] = column hl of Sigma^-1

        // dump inverse (own column) to wave-private LDS
        #pragma unroll
        for (int r = 0; r < DD; ++r) inv_s[r * 33 + hl] = a[r];

        // iv_c = (Sigma^-1 mu)_c from own column (symmetry) + LDS mu reads
        float ivr = 0.f;
        #pragma unroll
        for (int e = 0; e < DD; ++e) ivr = fmaf(a[e], mu_s[e], ivr);

        // bias = mu^T Sigma^-1 mu : butterfly sum within half
        float pb = mu_lane * ivr;
        pb += swzx<1>(pb); pb += swzx<2>(pb); pb += swzx<4>(pb);
        pb += swzx<8>(pb); pb += swzx<16>(pb);
        const float bias = pb;

        // Packed upper-triangle features (q-side carries the 0.25 JSD scale).
        for (int idx = hl; idx < UT; idx += 32) {
            int d = (int)((65.0f - sqrtf(4225.0f - 8.0f * (float)idx)) * 0.5f);
            if (d > 0 && (d * (65 - d)) / 2 > idx) --d;
            if (((d + 1) * (64 - d)) / 2 <= idx) ++d;
            int off = (d * (65 - d)) / 2;
            int e = d + (idx - off);
            float Mv = covp[d * DD + e] + mu_s[d] * mu_s[e];
            float Iv = inv_s[d * 33 + e];
            float w = (d == e) ? 0.25f : 0.5f;
            float v0, v1;
            if (qside) { v0 = w * Mv; v1 = w * Iv; }
            else       { v0 = Iv;     v1 = Mv; }
            ushort_t h0, h1, l0, l1;
            pk_split(v0, v1, h0, h1, l0, l1);
            fh[fo + idx] = h0; fh[fo + UT + idx] = h1;
            fl[fo + idx] = l0; fl[fo + UT + idx] = l1;
        }
        {
            float v0, v1;
            if (qside) { v0 = -0.5f * ivr; v1 = 0.25f * mu_lane; }
            else       { v0 = mu_lane;     v1 = -2.f * ivr; }
            ushort_t h0, h1, l0, l1;
            pk_split(v0, v1, h0, h1, l0, l1);
            fh[fo + 2*UT + hl] = h0; fh[fo + 2*UT + DD + hl] = h1;
            fl[fo + 2*UT + hl] = l0; fl[fo + 2*UT + DD + hl] = l1;
        }
        if (hl == 0) {
            float v = qside ? 0.25f : bias;
            ushort_t hb = f2bf(v);
            fh[fo + 2*UT + 2*DD] = hb;
            fl[fo + 2*UT + 2*DD] = f2bf(v - bf2f(hb));
        }
        for (int i = 2*UT + 2*DD + 1 + hl; i < KF; i += 32) { fh[fo + i] = 0; fl[fo + i] = 0; }
    } else {
        // ---- Vt transpose path ----
        float* sm = smem;                              // 32x33 tile
        const int vb = blockIdx.x - FEAT_BLOCKS;
        const int b = vb / (34 * 16), rem = vb % (34 * 16);
        const int kt = rem / 34, nt = rem % 34;
        const int n0 = nt * 32, k0 = kt * 32;
        const int tx = tid & 31, ty = tid >> 5;
        for (int r = ty; r < 32; r += 8) {             // coalesced over tx=n
            const int k = k0 + r, n = n0 + tx;
            float v;
            if (n0 == 0)          v = vmean[((size_t)b * SKL + k) * DD + n];
            else if (n0 >= NOUT)  v = 0.f;
            else                  v = vcov[((size_t)b * SKL + k) * (DD * DD) + (n - DD)];
            sm[tx * 33 + r] = v;
        }
        __syncthreads();
        for (int r = ty; r < 32; r += 8) {             // coalesced over tx=k
            const int n = n0 + r, k = k0 + tx;
            vth[((size_t)b * NVT + n) * SKL + k] = f2bf(sm[r * 33 + tx]);
        }
    }
}

// ---------------------------------------------------------------------------
// MFMA GEMM. MODE 0: score, A,B split hi/lo (3 MFMA/pair), split-K x2.
//   DUAL=1: kslice s plain-stores into Cs (no atomics, no pre-zero).
//   DUAL=0: atomicAdd into C0 (pre-zeroed) — ws-too-small fallback.
// MODE 1: output. A=P hi, B=Vt hi. Routed stores.
// ---------------------------------------------------------------------------
template<int MODE, int DUAL>
__global__ __launch_bounds__(256) void gemm_split(
    const ushort_t* __restrict__ Ah_g, const ushort_t* __restrict__ Al_g,
    const ushort_t* __restrict__ Bh_g, const ushort_t* __restrict__ Bl_g,
    float* __restrict__ C0, float* __restrict__ C1)
{
    constexpr bool SPLIT = (MODE == 0);
    constexpr int KSTRIDE = SPLIT ? KF : SKL;
    constexpr int KITERS = SPLIT ? (KF / 2 / 32) : (SKL / 32);
    const int b = blockIdx.z, nt = blockIdx.x;
    const int mt = SPLIT ? (blockIdx.y & 3) : blockIdx.y;
    const int ks = SPLIT ? (blockIdx.y >> 2) : 0;
    const int kbase = ks * (SPLIT ? (KF / 2) : 0);
    const int tid = threadIdx.x, lane = tid & 63, wid = tid >> 6;
    const int wm = wid & 1, wn = wid >> 1;
    const int BROWS = MODE ? NVT : SKL;

    const ushort_t* Ah = Ah_g + ((size_t)b * SQL + mt * 128) * KSTRIDE;
    const ushort_t* Al = Al_g + ((size_t)b * SQL + mt * 128) * KSTRIDE;
    const ushort_t* Bh = Bh_g + ((size_t)b * BROWS + nt * 64) * KSTRIDE;
    const ushort_t* Bl = Bl_g + ((size_t)b * BROWS + nt * 64) * KSTRIDE;

    __shared__ __align__(16) ushort_t AsH[128 * 32];
    __shared__ __align__(16) ushort_t AsL[SPLIT ? 128 * 32 : 8];
    __shared__ __align__(16) ushort_t BsH[64 * 32];
    __shared__ __align__(16) ushort_t BsL[SPLIT ? 64 * 32 : 8];

    const int r4 = lane >> 2, kp = (lane & 3) * 8;
    const int arow0 = wid * 16 + r4,        aoff0 = wid * 512 + lane * 8;
    const int arow1 = (wid + 4) * 16 + r4,  aoff1 = (wid + 4) * 512 + lane * 8;

    const int fm = lane & 15;
    const int q8 = (lane >> 4) * 8;

    f32x4 acc[4][2];
    #pragma unroll
    for (int i = 0; i < 4; ++i)
        #pragma unroll
        for (int j = 0; j < 2; ++j)
            acc[i][j] = (f32x4){0.f, 0.f, 0.f, 0.f};

    for (int it = 0; it < KITERS; ++it) {
        const int k0 = kbase + it * 32;
        __syncthreads();
        gl_lds16(Ah + (size_t)arow0 * KSTRIDE + k0 + kp, &AsH[aoff0]);
        gl_lds16(Ah + (size_t)arow1 * KSTRIDE + k0 + kp, &AsH[aoff1]);
        gl_lds16(Bh + (size_t)arow0 * KSTRIDE + k0 + kp, &BsH[aoff0]);
        if (SPLIT) {
            gl_lds16(Al + (size_t)arow0 * KSTRIDE + k0 + kp, &AsL[aoff0]);
            gl_lds16(Al + (size_t)arow1 * KSTRIDE + k0 + kp, &AsL[aoff1]);
            gl_lds16(Bl + (size_t)arow0 * KSTRIDE + k0 + kp, &BsL[aoff0]);
        }
        __syncthreads();

        short8 ah[4], al[4], bh[2], bl[2];
        #pragma unroll
        for (int i = 0; i < 4; ++i) {
            const int r = wm * 64 + i * 16 + fm;
            ah[i] = *(const short8*)&AsH[r * 32 + q8];
            if (SPLIT) al[i] = *(const short8*)&AsL[r * 32 + q8];
        }
        #pragma unroll
        for (int j = 0; j < 2; ++j) {
            const int r = wn * 32 + j * 16 + fm;
            bh[j] = *(const short8*)&BsH[r * 32 + q8];
            if (SPLIT) bl[j] = *(const short8*)&BsL[r * 32 + q8];
        }
        #pragma unroll
        for (int i = 0; i < 4; ++i)
            #pragma unroll
            for (int j = 0; j < 2; ++j) {
                acc[i][j] = __builtin_amdgcn_mfma_f32_16x16x32_bf16(ah[i], bh[j], acc[i][j], 0, 0, 0);
                if (SPLIT) {
                    acc[i][j] = __builtin_amdgcn_mfma_f32_16x16x32_bf16(ah[i], bl[j], acc[i][j], 0, 0, 0);
                    acc[i][j] = __builtin_amdgcn_mfma_f32_16x16x32_bf16(al[i], bh[j], acc[i][j], 0, 0, 0);
                }
            }
    }

    float* Cs = (SPLIT && DUAL && ks) ? C1 : C0;
    const int crow0 = (lane >> 4) * 4;
    const int ccol = lane & 15;
    #pragma unroll
    for (int i = 0; i < 4; ++i) {
        const int m = mt * 128 + wm * 64 + i * 16 + crow0;
        #pragma unroll
        for (int j = 0; j < 2; ++j) {
            const int n = nt * 64 + wn * 32 + j * 16 + ccol;
            #pragma unroll
            for (int r = 0; r < 4; ++r) {
                const float v = acc[i][j][r];
                const size_t rowb = (size_t)b * SQL + (m + r);
                if (MODE == 0) {
                    if (DUAL) Cs[rowb * SKL + n] = v;
                    else      atomicAdd(&C0[rowb * SKL + n], v);
                } else {
                    if (n < DD)        C0[rowb * DD + n] = v;
                    else if (n < NOUT) C1[rowb * (DD * DD) + (n - DD)] = v;
                }
            }
        }
    }
}

// ---------------------------------------------------------------------------
// Kernel 3: row softmax over (js0[+js1]) -> bf16 P (hi only).
// ---------------------------------------------------------------------------
template<int DUAL>
__global__ __launch_bounds__(256) void softmax_rows(
    const float* __restrict__ js0, const float* __restrict__ js1,
    ushort_t* __restrict__ ph)
{
    __shared__ float sm[8];
    const int tid = threadIdx.x;
    const size_t ro = (size_t)blockIdx.x * SKL + 2 * tid;
    float2 v = *(const float2*)(js0 + ro);
    if (DUAL) {
        float2 v1 = *(const float2*)(js1 + ro);
        v.x += v1.x; v.y += v1.y;
    }
    float m = fmaxf(v.x, v.y);
    #pragma unroll
    for (int o = 32; o > 0; o >>= 1) m = fmaxf(m, __shfl_xor(m, o));
    const int wid = tid >> 6, ln = tid & 63;
    if (ln == 0) sm[wid] = m;
    __syncthreads();
    m = fmaxf(fmaxf(sm[0], sm[1]), fmaxf(sm[2], sm[3]));
    float e0 = __expf(v.x - m), e1 = __expf(v.y - m);
    float s = e0 + e1;
    #pragma unroll
    for (int o = 32; o > 0; o >>= 1) s += __shfl_xor(s, o);
    if (ln == 0) sm[4 + wid] = s;
    __syncthreads();
    s = sm[4] + sm[5] + sm[6] + sm[7];
    float rs = 1.0f / s;
    ph[ro]     = f2bf(e0 * rs);
    ph[ro + 1] = f2bf(e1 * rs);
}

// ---------------------------------------------------------------------------
extern "C" void kernel_launch(void* const* d_in, const int* in_sizes, int n_in,
                              void* d_out, int out_size, void* d_ws, size_t ws_size,
                              hipStream_t stream)
{
    const float* q_mean = (const float*)d_in[0];
    const float* q_cov  = (const float*)d_in[1];
    const float* k_mean = (const float*)d_in[2];
    const float* k_cov  = (const float*)d_in[3];
    const float* v_mean = (const float*)d_in[4];
    const float* v_cov  = (const float*)d_in[5];

    float* out_mean = (float*)d_out;                        // [8,512,32]
    float* out_cov  = out_mean + (size_t)NBATCH * SQL * DD; // [8,512,32,32]

    // workspace: features 37.7MB | js0 8.4 | [js1 8.4] | vt 8.9  (<= 63.4MB)
    // vt gets its own region: written concurrently with feat (fused tail).
    char* w = (char*)d_ws;
    const size_t FQN = (size_t)NBATCH * SQL * KF;
    const size_t JSN = (size_t)NBATCH * SQL * SKL;
    const size_t VTN = (size_t)NBATCH * NVT * SKL;
    ushort_t* fq_h = (ushort_t*)w;
    ushort_t* fq_l = fq_h + FQN;
    ushort_t* fk_h = fq_l + FQN;
    ushort_t* fk_l = fk_h + FQN;
    float*    js0  = (float*)(fk_l + FQN);
    const bool dual = ws_size >= (8 * FQN + 8 * JSN + 2 * VTN);
    float*    js1  = dual ? (js0 + JSN) : nullptr;
    ushort_t* vt_h = (ushort_t*)(js0 + (dual ? 2 : 1) * JSN);
    ushort_t* p_h  = fk_h;              // features dead after score gemm

    feat_fused<<<FEAT_BLOCKS + VS_BLOCKS, 256, 0, stream>>>(
        q_mean, q_cov, k_mean, k_cov, fq_h, fq_l, fk_h, fk_l,
        v_mean, v_cov, vt_h);
    if (dual) {
        gemm_split<0, 1><<<dim3(SKL / 64, 8, NBATCH), 256, 0, stream>>>(
            fq_h, fq_l, fk_h, fk_l, js0, js1);
        softmax_rows<1><<<NBATCH * SQL, 256, 0, stream>>>(js0, js1, p_h);
    } else {
        hipMemsetAsync(js0, 0, JSN * sizeof(float), stream);
        gemm_split<0, 0><<<dim3(SKL / 64, 8, NBATCH), 256, 0, stream>>>(
            fq_h, fq_l, fk_h, fk_l, js0, nullptr);
        softmax_rows<0><<<NBATCH * SQL, 256, 0, stream>>>(js0, nullptr, p_h);
    }
    gemm_split<1, 0><<<dim3(NVT / 64, SQL / 128, NBATCH), 256, 0, stream>>>(
        p_h, nullptr, vt_h, nullptr, out_mean, out_cov);
}

// Round 11
// 182.575 us; speedup vs baseline: 2.7431x; 1.0093x over previous
//
#include <hip/hip_runtime.h>
#include <hip/hip_bf16.h>

#define NBATCH 8
#define SQL 512
#define SKL 512
#define DD 32
#define KF 1152            // padded feature dim (real 1121)
#define UT 528             // D*(D+1)/2
#define NOUT 1056          // 32 mean cols + 1024 cov cols
#define NVT 1088           // Vt rows padded to 17*64
#define NSITE (NBATCH * SQL)        // 4096 per side
#define FEAT_BLOCKS (2 * NSITE / 8) // 1024 blocks, 8 matrices each
#define VS_BLOCKS (34 * 16 * NBATCH)

typedef short short8 __attribute__((ext_vector_type(8)));   // 8 bf16 bit-patterns
typedef float f32x4 __attribute__((ext_vector_type(4)));
typedef unsigned short ushort_t;

__device__ __forceinline__ ushort_t f2bf(float f) {          // fp32 -> bf16 bits, RNE
    unsigned int u = __float_as_uint(f);
    return (ushort_t)((u + 0x7fffu + ((u >> 16) & 1u)) >> 16);
}
__device__ __forceinline__ float bf2f(ushort_t h) {
    return __uint_as_float(((unsigned int)h) << 16);
}
__device__ __forceinline__ void gl_lds16(const ushort_t* g, ushort_t* l) {
    __builtin_amdgcn_global_load_lds(
        (const __attribute__((address_space(1))) void*)g,
        (__attribute__((address_space(3))) void*)l, 16, 0, 0);
}
// packed 2x fp32 -> bf16 hi bits + lo residual bits
__device__ __forceinline__ void pk_split(float v0, float v1, ushort_t& h0, ushort_t& h1,
                                         ushort_t& l0, ushort_t& l1) {
    __hip_bfloat162 H = __float22bfloat162_rn(make_float2(v0, v1));
    ushort2 hu = *(ushort2*)&H;
    h0 = hu.x; h1 = hu.y;
    __hip_bfloat162 L = __float22bfloat162_rn(make_float2(v0 - bf2f(hu.x), v1 - bf2f(hu.y)));
    ushort2 lu = *(ushort2*)&L;
    l0 = lu.x; l1 = lu.y;
}

// ds_swizzle BitMode broadcast of lane P within each 32-lane half
template<int P>
__device__ __forceinline__ float swzb(float x) {
    return __int_as_float(__builtin_amdgcn_ds_swizzle(__float_as_int(x), (P << 5)));
}
// butterfly xor-M within each 32-lane half (and=0x1F)
template<int M>
__device__ __forceinline__ float swzx(float x) {
    return __int_as_float(__builtin_amdgcn_ds_swizzle(__float_as_int(x), (M << 10) | 0x1F));
}

// In-place symmetric GJ sweep, one pivot (R6-proven: VGPR=52, no spill).
// Lane hl (0..31 per half) holds column hl. After 32 pivots, a[] = column hl
// of A^-1. Broadcasts via ds_swizzle: register-to-register on the DS pipe —
// LDS round-trip variants spill a[32] (R8/R9 post-mortem).
template<int P>
__device__ __forceinline__ void gj_step(float (&a)[DD], int hl) {
    float piv = swzb<P>(a[P]);
    float rinv = __builtin_amdgcn_rcpf(piv);   // SPD, cond~2: rcp fine
    float t = a[P] * rinv;
    bool isp = (hl == P);
    float u = isp ? rinv : t;
    float g = isp ? 0.0f : 1.0f;
    #pragma unroll
    for (int i = 0; i < DD; ++i) {
        if (i == P) continue;
        float ci = swzb<P>(a[i]);              // a_iP (per half), pre-update
        a[i] = fmaf(a[i], g, -(ci * u));
    }
    a[P] = u;
}
template<int P>
__device__ __forceinline__ void gj_run(float (&a)[DD], int hl) {
    gj_step<P>(a, hl);
    if constexpr (P + 1 < DD) gj_run<P + 1>(a, hl);
}

// ---------------------------------------------------------------------------
// Kernel 1 (fused): blocks [0, VS_BLOCKS): Vt transpose — FIRST in the grid
// so the cheap memory-bound blocks drain while feat blocks stream in behind
// them (R10 post-mortem: feat-first serialized the tail, +50us).
// blocks [VS_BLOCKS, ..): per-site inversion + bf16 hi/lo features
// (8 matrices/block, 2 per wave, swizzle GJ, wave-private LDS, no barriers).
// ---------------------------------------------------------------------------
__global__ __launch_bounds__(256, 4) void feat_fused(
    const float* __restrict__ qm, const float* __restrict__ qc,
    const float* __restrict__ km, const float* __restrict__ kc,
    ushort_t* __restrict__ fqh, ushort_t* __restrict__ fql,
    ushort_t* __restrict__ fkh, ushort_t* __restrict__ fkl,
    const float* __restrict__ vmean, const float* __restrict__ vcov,
    ushort_t* __restrict__ vth)
{
    __shared__ float smem[8 * 1064 + 8 * 32];   // feat: 8x(32x33 inv) + 8x32 mu
    const int tid = threadIdx.x;

    if (blockIdx.x >= VS_BLOCKS) {
        const int fb = blockIdx.x - VS_BLOCKS;                  // 0..1023
        const int wid = tid >> 6, lane = tid & 63;
        const int half = lane >> 5, hl = lane & 31;
        const int site_g = (fb * 4 + wid) * 2 + half;           // 0..8191
        const int qside = site_g < NSITE;
        const int site = qside ? site_g : site_g - NSITE;

        const float* covp = (qside ? qc : kc) + (size_t)site * (DD * DD);
        const float* mup  = (qside ? qm : km) + (size_t)site * DD;
        ushort_t* fh = qside ? fqh : fkh;
        ushort_t* fl = qside ? fql : fkl;
        const size_t fo = (size_t)site * KF;

        float* inv_s = smem + (wid * 2 + half) * 1064;          // row stride 33
        float* mu_s  = smem + 8 * 1064 + (wid * 2 + half) * 32;

        const float mu_lane = mup[hl];
        mu_s[hl] = mu_lane;

        float a[DD];
        #pragma unroll
        for (int r = 0; r < DD; ++r) a[r] = covp[r * DD + hl];

        gj_run<0>(a, hl);              // a[] = column hl of Sigma^-1

        // dump inverse (own column) to wave-private LDS
        #pragma unroll
        for (int r = 0; r < DD; ++r) inv_s[r * 33 + hl] = a[r];

        // iv_c = (Sigma^-1 mu)_c from own column (symmetry) + LDS mu reads
        float ivr = 0.f;
        #pragma unroll
        for (int e = 0; e < DD; ++e) ivr = fmaf(a[e], mu_s[e], ivr);

        // bias = mu^T Sigma^-1 mu : butterfly sum within half
        float pb = mu_lane * ivr;
        pb += swzx<1>(pb); pb += swzx<2>(pb); pb += swzx<4>(pb);
        pb += swzx<8>(pb); pb += swzx<16>(pb);
        const float bias = pb;

        // Packed upper-triangle features (q-side carries the 0.25 JSD scale).
        for (int idx = hl; idx < UT; idx += 32) {
            int d = (int)((65.0f - sqrtf(4225.0f - 8.0f * (float)idx)) * 0.5f);
            if (d > 0 && (d * (65 - d)) / 2 > idx) --d;
            if (((d + 1) * (64 - d)) / 2 <= idx) ++d;
            int off = (d * (65 - d)) / 2;
            int e = d + (idx - off);
            float Mv = covp[d * DD + e] + mu_s[d] * mu_s[e];
            float Iv = inv_s[d * 33 + e];
            float w = (d == e) ? 0.25f : 0.5f;
            float v0, v1;
            if (qside) { v0 = w * Mv; v1 = w * Iv; }
            else       { v0 = Iv;     v1 = Mv; }
            ushort_t h0, h1, l0, l1;
            pk_split(v0, v1, h0, h1, l0, l1);
            fh[fo + idx] = h0; fh[fo + UT + idx] = h1;
            fl[fo + idx] = l0; fl[fo + UT + idx] = l1;
        }
        {
            float v0, v1;
            if (qside) { v0 = -0.5f * ivr; v1 = 0.25f * mu_lane; }
            else       { v0 = mu_lane;     v1 = -2.f * ivr; }
            ushort_t h0, h1, l0, l1;
            pk_split(v0, v1, h0, h1, l0, l1);
            fh[fo + 2*UT + hl] = h0; fh[fo + 2*UT + DD + hl] = h1;
            fl[fo + 2*UT + hl] = l0; fl[fo + 2*UT + DD + hl] = l1;
        }
        if (hl == 0) {
            float v = qside ? 0.25f : bias;
            ushort_t hb = f2bf(v);
            fh[fo + 2*UT + 2*DD] = hb;
            fl[fo + 2*UT + 2*DD] = f2bf(v - bf2f(hb));
        }
        for (int i = 2*UT + 2*DD + 1 + hl; i < KF; i += 32) { fh[fo + i] = 0; fl[fo + i] = 0; }
    } else {
        // ---- Vt transpose path (first in grid) ----
        float* sm = smem;                              // 32x33 tile
        const int vb = blockIdx.x;
        const int b = vb / (34 * 16), rem = vb % (34 * 16);
        const int kt = rem / 34, nt = rem % 34;
        const int n0 = nt * 32, k0 = kt * 32;
        const int tx = tid & 31, ty = tid >> 5;
        for (int r = ty; r < 32; r += 8) {             // coalesced over tx=n
            const int k = k0 + r, n = n0 + tx;
            float v;
            if (n0 == 0)          v = vmean[((size_t)b * SKL + k) * DD + n];
            else if (n0 >= NOUT)  v = 0.f;
            else                  v = vcov[((size_t)b * SKL + k) * (DD * DD) + (n - DD)];
            sm[tx * 33 + r] = v;
        }
        __syncthreads();
        for (int r = ty; r < 32; r += 8) {             // coalesced over tx=k
            const int n = n0 + r, k = k0 + tx;
            vth[((size_t)b * NVT + n) * SKL + k] = f2bf(sm[r * 33 + tx]);
        }
    }
}

// ---------------------------------------------------------------------------
// MFMA GEMM. MODE 0: score, A,B split hi/lo (3 MFMA/pair), split-K x2.
//   DUAL=1: kslice s plain-stores into Cs (no atomics, no pre-zero).
//   DUAL=0: atomicAdd into C0 (pre-zeroed) — ws-too-small fallback.
// MODE 1: output. A=P hi, B=Vt hi. Routed stores.
// ---------------------------------------------------------------------------
template<int MODE, int DUAL>
__global__ __launch_bounds__(256) void gemm_split(
    const ushort_t* __restrict__ Ah_g, const ushort_t* __restrict__ Al_g,
    const ushort_t* __restrict__ Bh_g, const ushort_t* __restrict__ Bl_g,
    float* __restrict__ C0, float* __restrict__ C1)
{
    constexpr bool SPLIT = (MODE == 0);
    constexpr int KSTRIDE = SPLIT ? KF : SKL;
    constexpr int KITERS = SPLIT ? (KF / 2 / 32) : (SKL / 32);
    const int b = blockIdx.z, nt = blockIdx.x;
    const int mt = SPLIT ? (blockIdx.y & 3) : blockIdx.y;
    const int ks = SPLIT ? (blockIdx.y >> 2) : 0;
    const int kbase = ks * (SPLIT ? (KF / 2) : 0);
    const int tid = threadIdx.x, lane = tid & 63, wid = tid >> 6;
    const int wm = wid & 1, wn = wid >> 1;
    const int BROWS = MODE ? NVT : SKL;

    const ushort_t* Ah = Ah_g + ((size_t)b * SQL + mt * 128) * KSTRIDE;
    const ushort_t* Al = Al_g + ((size_t)b * SQL + mt * 128) * KSTRIDE;
    const ushort_t* Bh = Bh_g + ((size_t)b * BROWS + nt * 64) * KSTRIDE;
    const ushort_t* Bl = Bl_g + ((size_t)b * BROWS + nt * 64) * KSTRIDE;

    __shared__ __align__(16) ushort_t AsH[128 * 32];
    __shared__ __align__(16) ushort_t AsL[SPLIT ? 128 * 32 : 8];
    __shared__ __align__(16) ushort_t BsH[64 * 32];
    __shared__ __align__(16) ushort_t BsL[SPLIT ? 64 * 32 : 8];

    const int r4 = lane >> 2, kp = (lane & 3) * 8;
    const int arow0 = wid * 16 + r4,        aoff0 = wid * 512 + lane * 8;
    const int arow1 = (wid + 4) * 16 + r4,  aoff1 = (wid + 4) * 512 + lane * 8;

    const int fm = lane & 15;
    const int q8 = (lane >> 4) * 8;

    f32x4 acc[4][2];
    #pragma unroll
    for (int i = 0; i < 4; ++i)
        #pragma unroll
        for (int j = 0; j < 2; ++j)
            acc[i][j] = (f32x4){0.f, 0.f, 0.f, 0.f};

    for (int it = 0; it < KITERS; ++it) {
        const int k0 = kbase + it * 32;
        __syncthreads();
        gl_lds16(Ah + (size_t)arow0 * KSTRIDE + k0 + kp, &AsH[aoff0]);
        gl_lds16(Ah + (size_t)arow1 * KSTRIDE + k0 + kp, &AsH[aoff1]);
        gl_lds16(Bh + (size_t)arow0 * KSTRIDE + k0 + kp, &BsH[aoff0]);
        if (SPLIT) {
            gl_lds16(Al + (size_t)arow0 * KSTRIDE + k0 + kp, &AsL[aoff0]);
            gl_lds16(Al + (size_t)arow1 * KSTRIDE + k0 + kp, &AsL[aoff1]);
            gl_lds16(Bl + (size_t)arow0 * KSTRIDE + k0 + kp, &BsL[aoff0]);
        }
        __syncthreads();

        short8 ah[4], al[4], bh[2], bl[2];
        #pragma unroll
        for (int i = 0; i < 4; ++i) {
            const int r = wm * 64 + i * 16 + fm;
            ah[i] = *(const short8*)&AsH[r * 32 + q8];
            if (SPLIT) al[i] = *(const short8*)&AsL[r * 32 + q8];
        }
        #pragma unroll
        for (int j = 0; j < 2; ++j) {
            const int r = wn * 32 + j * 16 + fm;
            bh[j] = *(const short8*)&BsH[r * 32 + q8];
            if (SPLIT) bl[j] = *(const short8*)&BsL[r * 32 + q8];
        }
        #pragma unroll
        for (int i = 0; i < 4; ++i)
            #pragma unroll
            for (int j = 0; j < 2; ++j) {
                acc[i][j] = __builtin_amdgcn_mfma_f32_16x16x32_bf16(ah[i], bh[j], acc[i][j], 0, 0, 0);
                if (SPLIT) {
                    acc[i][j] = __builtin_amdgcn_mfma_f32_16x16x32_bf16(ah[i], bl[j], acc[i][j], 0, 0, 0);
                    acc[i][j] = __builtin_amdgcn_mfma_f32_16x16x32_bf16(al[i], bh[j], acc[i][j], 0, 0, 0);
                }
            }
    }

    float* Cs = (SPLIT && DUAL && ks) ? C1 : C0;
    const int crow0 = (lane >> 4) * 4;
    const int ccol = lane & 15;
    #pragma unroll
    for (int i = 0; i < 4; ++i) {
        const int m = mt * 128 + wm * 64 + i * 16 + crow0;
        #pragma unroll
        for (int j = 0; j < 2; ++j) {
            const int n = nt * 64 + wn * 32 + j * 16 + ccol;
            #pragma unroll
            for (int r = 0; r < 4; ++r) {
                const float v = acc[i][j][r];
                const size_t rowb = (size_t)b * SQL + (m + r);
                if (MODE == 0) {
                    if (DUAL) Cs[rowb * SKL + n] = v;
                    else      atomicAdd(&C0[rowb * SKL + n], v);
                } else {
                    if (n < DD)        C0[rowb * DD + n] = v;
                    else if (n < NOUT) C1[rowb * (DD * DD) + (n - DD)] = v;
                }
            }
        }
    }
}

// ---------------------------------------------------------------------------
// Kernel 3: row softmax over (js0[+js1]) -> bf16 P (hi only).
// ---------------------------------------------------------------------------
template<int DUAL>
__global__ __launch_bounds__(256) void softmax_rows(
    const float* __restrict__ js0, const float* __restrict__ js1,
    ushort_t* __restrict__ ph)
{
    __shared__ float sm[8];
    const int tid = threadIdx.x;
    const size_t ro = (size_t)blockIdx.x * SKL + 2 * tid;
    float2 v = *(const float2*)(js0 + ro);
    if (DUAL) {
        float2 v1 = *(const float2*)(js1 + ro);
        v.x += v1.x; v.y += v1.y;
    }
    float m = fmaxf(v.x, v.y);
    #pragma unroll
    for (int o = 32; o > 0; o >>= 1) m = fmaxf(m, __shfl_xor(m, o));
    const int wid = tid >> 6, ln = tid & 63;
    if (ln == 0) sm[wid] = m;
    __syncthreads();
    m = fmaxf(fmaxf(sm[0], sm[1]), fmaxf(sm[2], sm[3]));
    float e0 = __expf(v.x - m), e1 = __expf(v.y - m);
    float s = e0 + e1;
    #pragma unroll
    for (int o = 32; o > 0; o >>= 1) s += __shfl_xor(s, o);
    if (ln == 0) sm[4 + wid] = s;
    __syncthreads();
    s = sm[4] + sm[5] + sm[6] + sm[7];
    float rs = 1.0f / s;
    ph[ro]     = f2bf(e0 * rs);
    ph[ro + 1] = f2bf(e1 * rs);
}

// ---------------------------------------------------------------------------
extern "C" void kernel_launch(void* const* d_in, const int* in_sizes, int n_in,
                              void* d_out, int out_size, void* d_ws, size_t ws_size,
                              hipStream_t stream)
{
    const float* q_mean = (const float*)d_in[0];
    const float* q_cov  = (const float*)d_in[1];
    const float* k_mean = (const float*)d_in[2];
    const float* k_cov  = (const float*)d_in[3];
    const float* v_mean = (const float*)d_in[4];
    const float* v_cov  = (const float*)d_in[5];

    float* out_mean = (float*)d_out;                        // [8,512,32]
    float* out_cov  = out_mean + (size_t)NBATCH * SQL * DD; // [8,512,32,32]

    // workspace: features 37.7MB | js0 8.4 | [js1 8.4] | vt 8.9  (<= 63.4MB)
    char* w = (char*)d_ws;
    const size_t FQN = (size_t)NBATCH * SQL * KF;
    const size_t JSN = (size_t)NBATCH * SQL * SKL;
    const size_t VTN = (size_t)NBATCH * NVT * SKL;
    ushort_t* fq_h = (ushort_t*)w;
    ushort_t* fq_l = fq_h + FQN;
    ushort_t* fk_h = fq_l + FQN;
    ushort_t* fk_l = fk_h + FQN;
    float*    js0  = (float*)(fk_l + FQN);
    const bool dual = ws_size >= (8 * FQN + 8 * JSN + 2 * VTN);
    float*    js1  = dual ? (js0 + JSN) : nullptr;
    ushort_t* vt_h = (ushort_t*)(js0 + (dual ? 2 : 1) * JSN);
    ushort_t* p_h  = fk_h;              // features dead after score gemm

    feat_fused<<<FEAT_BLOCKS + VS_BLOCKS, 256, 0, stream>>>(
        q_mean, q_cov, k_mean, k_cov, fq_h, fq_l, fk_h, fk_l,
        v_mean, v_cov, vt_h);
    if (dual) {
        gemm_split<0, 1><<<dim3(SKL / 64, 8, NBATCH), 256, 0, stream>>>(
            fq_h, fq_l, fk_h, fk_l, js0, js1);
        softmax_rows<1><<<NBATCH * SQL, 256, 0, stream>>>(js0, js1, p_h);
    } else {
        hipMemsetAsync(js0, 0, JSN * sizeof(float), stream);
        gemm_split<0, 0><<<dim3(SKL / 64, 8, NBATCH), 256, 0, stream>>>(
            fq_h, fq_l, fk_h, fk_l, js0, nullptr);
        softmax_rows<0><<<NBATCH * SQL, 256, 0, stream>>>(js0, nullptr, p_h);
    }
    gemm_split<1, 0><<<dim3(NVT / 64, SQL / 128, NBATCH), 256, 0, stream>>>(
        p_h, nullptr, vt_h, nullptr, out_mean, out_cov);
}